// Round 10
// baseline (217.627 us; speedup 1.0000x reference)
//
#include <hip/hip_runtime.h>
#include <math.h>

#define NUM_EMB 8192
#define DIM     64
#define NBATCH  4
#define NVOX    32768
#define TPB     256
#define NSPLIT  4                 // codebook splits (blocks per voxel-group)
#define EPB     (NUM_EMB / NSPLIT)
#define CHUNK   64                // entries staged per iteration
#define NCH     (EPB / CHUNK)     // 32 chunks
#define BUFSZ   (CHUNK * 128 * 2 + CHUNK * 4)   // lbh 8K | lbm 8K | cn 256B
#define CERT_EPS 0.015f           // v-space gap threshold (err bound ~3.2e-3)
#define RCH     512               // repair: entries per (row,chunk) work item

// output layout (f32, concatenated in return order)
#define OFF_Q     0            // 32768*64
#define OFF_VQ    2097152
#define OFF_COMM  2097153
#define OFF_IDX   2097154      // 32768
#define OFF_PERP  2129922
#define OFF_ENT   2129923
#define OFF_UNIQ  2129924
#define OFF_UTIL  2129925

typedef __bf16 bf16x8 __attribute__((ext_vector_type(8)));
typedef float  f32x4  __attribute__((ext_vector_type(4)));

__device__ __forceinline__ unsigned short f2bf(float f) {   // RNE f32->bf16
    unsigned u = __float_as_uint(f);
    unsigned r = u + 0x7FFFu + ((u >> 16) & 1u);
    return (unsigned short)(r >> 16);
}
__device__ __forceinline__ float bf2f(unsigned short h) {
    return __uint_as_float(((unsigned)h) << 16);
}
// monotone float -> sortable uint (non-NaN)
__device__ __forceinline__ unsigned fmap(float f) {
    unsigned u = __float_as_uint(f);
    return (u & 0x80000000u) ? ~u : (u | 0x80000000u);
}

// prep: bf16 2-split of codebook, scalar -||c||^2/2, all scratch init,
// and zeroing of the 6 scalar outputs (poisoned 0xAA; stats atomicAdds).
__global__ void prep_kernel(const float* __restrict__ cb,
                            unsigned short* __restrict__ cbh,
                            unsigned short* __restrict__ cbm,
                            float* __restrict__ cnn,
                            unsigned* __restrict__ counts,
                            unsigned* __restrict__ misc,
                            unsigned long long* __restrict__ merge,
                            float* __restrict__ out) {
    int row = blockIdx.x * 4 + (threadIdx.x >> 6);
    int l   = threadIdx.x & 63;
    float f = cb[row * DIM + l];
    unsigned short hh = f2bf(f); float r1 = f - bf2f(hh);
    cbh[row * DIM + l] = hh;
    cbm[row * DIM + l] = f2bf(r1);
    float s = f * f;
#pragma unroll
    for (int o = 32; o > 0; o >>= 1) s += __shfl_xor(s, o, 64);
    if (l == 0) cnn[row] = -0.5f * s;

    int gid = blockIdx.x * TPB + threadIdx.x;       // 0..524287
    if (gid < NBATCH * NUM_EMB) counts[gid] = 0;
    if (gid >= 32768 && gid < 65536) merge[gid - 32768] = ~0ull;
    if (gid < 16) misc[gid] = 0;                    // lcount, sqsum, pad
    if (blockIdx.x == 0) {
        if (threadIdx.x < 2) out[OFF_VQ + threadIdx.x] = 0.f;
        if (threadIdx.x < 4) out[OFF_PERP + threadIdx.x] = 0.f;
    }
}

// Single-pass 3-product (hh,hm,mh) MFMA scan.
// r10: (a) waves_per_eu(4,4) -> 128-VGPR budget, kill phantom accvgpr moves
//      (r9 PM: VALUBusy 53% at VGPR_Count=60, 3-4x static VALU count);
//      (b) double-buffered LDS, next-chunk global loads issued before compute;
//      (c) cn as scalar ds_read_b32 + splat (5 -> 4 b128 reads per tile).
__global__ __launch_bounds__(TPB)
__attribute__((amdgpu_waves_per_eu(4, 4)))
void argmin_kernel(
        const float* __restrict__ z,
        const unsigned short* __restrict__ cbh,
        const unsigned short* __restrict__ cbm,
        const float* __restrict__ cnn,
        float4* __restrict__ res) {
    __shared__ __align__(16) char lds[2 * BUFSZ];

    const int t  = threadIdx.x;
    const int l  = t & 63, w = t >> 6;
    const int lc = l & 15, lg = l >> 4;
    const int vb = blockIdx.x >> 2, qh = blockIdx.x & 3;
    const int ebase = qh * EPB;

    union U { bf16x8 v; unsigned short s[8]; };
    U Ah[2][2], Am[2][2];                // on-the-fly 2-split of 32 z rows
#pragma unroll
    for (int set = 0; set < 2; ++set) {
        const float* zp = z + (size_t)(vb * 128 + w * 32 + set * 16 + lc) * DIM + lg * 8;
#pragma unroll
        for (int ks = 0; ks < 2; ++ks)
#pragma unroll
            for (int j = 0; j < 8; ++j) {
                float f = zp[ks * 32 + j];
                unsigned short hh = f2bf(f);
                Ah[set][ks].s[j] = hh;
                Am[set][ks].s[j] = f2bf(f - bf2f(hh));
            }
    }

    float m1[2][4], m2[2][4]; int ix[2][4];
#pragma unroll
    for (int set = 0; set < 2; ++set)
#pragma unroll
        for (int r = 0; r < 4; ++r) {
            m1[set][r] = -INFINITY; m2[set][r] = -INFINITY; ix[set][r] = 0;
        }

    // per-lane LDS read bases: XOR-swizzle folded once; k-step1 = base ^ 64
    const int b0 = (lc * 128 + lg * 16) ^ ((lc & 7) << 4);
    const int b1 = b0 ^ 64;

    // staging registers (held across compute: global latency hides under MFMA)
    uint4 rh0, rh1, rm0, rm1; float rc;
#define STAGE_LOAD(CH) {                                                      \
        const uint4* sh = (const uint4*)(cbh + (size_t)(ebase + (CH) * CHUNK) * DIM); \
        const uint4* sm = (const uint4*)(cbm + (size_t)(ebase + (CH) * CHUNK) * DIM); \
        rh0 = sh[t]; rh1 = sh[t + 256];                                       \
        rm0 = sm[t]; rm1 = sm[t + 256];                                       \
        if (t < CHUNK) rc = cnn[ebase + (CH) * CHUNK + t];                    \
    }
#define STAGE_WRITE(BUF) {                                                    \
        int o0 = t * 16, o1 = (256 + t) * 16;                                 \
        int s0 = o0 ^ (((o0 >> 7) & 7) << 4);                                 \
        int s1 = o1 ^ (((o1 >> 7) & 7) << 4);                                 \
        *(uint4*)((BUF) + s0) = rh0;  *(uint4*)((BUF) + s1) = rh1;            \
        *(uint4*)((BUF) + 8192 + s0) = rm0; *(uint4*)((BUF) + 8192 + s1) = rm1; \
        if (t < CHUNK) ((float*)((BUF) + 16384))[t] = rc;                     \
    }

    STAGE_LOAD(0);
    STAGE_WRITE(lds);
    __syncthreads();

    for (int ch = 0; ch < NCH; ++ch) {
        char* cur = lds + (ch & 1) * BUFSZ;
        if (ch + 1 < NCH) STAGE_LOAD(ch + 1);      // issue early, hide latency

        int e0 = ebase + ch * CHUNK + lc;
#pragma unroll
        for (int tile = 0; tile < CHUNK / 16; ++tile) {
            bf16x8 bh0 = *(const bf16x8*)(cur + b0 + tile * 2048);
            bf16x8 bh1 = *(const bf16x8*)(cur + b1 + tile * 2048);
            bf16x8 bm0 = *(const bf16x8*)(cur + 8192 + b0 + tile * 2048);
            bf16x8 bm1 = *(const bf16x8*)(cur + 8192 + b1 + tile * 2048);
            float  cnv = *(const float*)(cur + 16384 + (tile * 16 + lc) * 4);
            f32x4 c0 = {cnv, cnv, cnv, cnv};
            int eidx = e0 + tile * 16;
#pragma unroll
            for (int set = 0; set < 2; ++set) {
                f32x4 a = c0;                     // C-init = -||c||^2/2
                a = __builtin_amdgcn_mfma_f32_16x16x32_bf16(Ah[set][0].v, bh0, a, 0, 0, 0);
                a = __builtin_amdgcn_mfma_f32_16x16x32_bf16(Am[set][0].v, bh0, a, 0, 0, 0);
                a = __builtin_amdgcn_mfma_f32_16x16x32_bf16(Ah[set][0].v, bm0, a, 0, 0, 0);
                a = __builtin_amdgcn_mfma_f32_16x16x32_bf16(Ah[set][1].v, bh1, a, 0, 0, 0);
                a = __builtin_amdgcn_mfma_f32_16x16x32_bf16(Am[set][1].v, bh1, a, 0, 0, 0);
                a = __builtin_amdgcn_mfma_f32_16x16x32_bf16(Ah[set][1].v, bm1, a, 0, 0, 0);
#pragma unroll
                for (int r = 0; r < 4; ++r) {     // D: col=lc, row=lg*4+r (m89)
                    float v = a[r];               // = z.c - ||c||^2/2 exactly
                    m2[set][r] = __builtin_amdgcn_fmed3f(v, m1[set][r], m2[set][r]);
                    if (v > m1[set][r]) { m1[set][r] = v; ix[set][r] = eidx; }
                }
            }
        }
        __syncthreads();                           // all reads of cur done
        if (ch + 1 < NCH) {
            STAGE_WRITE(lds + ((ch + 1) & 1) * BUFSZ);
            __syncthreads();                       // next buffer visible
        }
    }

    // reduce (max1,idx,max2) across the 16 column-lanes, lowest-idx tiebreak
#pragma unroll
    for (int set = 0; set < 2; ++set)
#pragma unroll
        for (int r = 0; r < 4; ++r) {
            float v1 = m1[set][r], v2 = m2[set][r]; int i1 = ix[set][r];
#pragma unroll
            for (int st = 1; st < 16; st <<= 1) {
                float o1 = __shfl_xor(v1, st, 16);
                float o2 = __shfl_xor(v2, st, 16);
                int   oi = __shfl_xor(i1, st, 16);
                float mn = fminf(v1, o1);
                v2 = fmaxf(fmaxf(v2, o2), mn);
                if (o1 > v1 || (o1 == v1 && oi < i1)) { v1 = o1; i1 = oi; }
            }
            if (lc == 0) {
                int vox = vb * 128 + w * 32 + set * 16 + lg * 4 + r;
                res[(size_t)qh * NVOX + vox] =
                    make_float4(v1, v2, __int_as_float(i1), 0.f);
            }
        }
}

// ---- path B (small ws): combine then gather, res in d_out ----
__global__ void combine_kernel(const float4* __restrict__ res, float* __restrict__ out) {
    int vox = blockIdx.x * blockDim.x + threadIdx.x;
    float v1 = -INFINITY, v2 = -INFINITY; int idx = 0;
#pragma unroll
    for (int h = 0; h < NSPLIT; ++h) {
        float4 t4 = res[(size_t)h * NVOX + vox];
        float a1 = t4.x, a2 = t4.y; int ai = __float_as_int(t4.z);
        float mn = fminf(v1, a1);
        v2 = fmaxf(fmaxf(v2, a2), mn);
        if (a1 > v1) { v1 = a1; idx = ai; }   // strict >: earlier split wins ties
    }
    unsigned flag = (v1 - v2 < CERT_EPS) ? 0x80000000u : 0u;
    ((unsigned*)out)[OFF_IDX + vox] = (unsigned)idx | flag;
}

__global__ void gather_kernel(const float* __restrict__ z, const int* __restrict__ zc,
        const float* __restrict__ cb, float* __restrict__ out,
        unsigned* __restrict__ counts, float* __restrict__ sqsum,
        unsigned* __restrict__ list, unsigned* __restrict__ lcount) {
    int vox = blockIdx.x * blockDim.x + threadIdx.x;
    unsigned pk = ((unsigned*)out)[OFF_IDX + vox];
    float s = 0.f;
    if (pk & 0x80000000u) {
        unsigned pos = atomicAdd(lcount, 1u);
        list[pos] = vox;
    } else {
        unsigned idx = pk;
        const float4* crow = (const float4*)(cb + (size_t)idx * DIM);
        const float4* zrow = (const float4*)(z + (size_t)vox * DIM);
        float4* qrow = (float4*)(out + OFF_Q + (size_t)vox * DIM);
#pragma unroll
        for (int i = 0; i < DIM / 4; ++i) {
            float4 c4 = crow[i];
            float4 z4 = zrow[i];
            float dx = z4.x - c4.x, dy = z4.y - c4.y;
            float dz = z4.z - c4.z, dw = z4.w - c4.w;
            s += dx * dx + dy * dy + dz * dz + dw * dw;
            qrow[i] = c4;
        }
        out[OFF_IDX + vox] = (float)idx;
        atomicAdd(&counts[zc[vox * 4] * NUM_EMB + idx], 1u);
    }
#pragma unroll
    for (int o = 32; o > 0; o >>= 1) s += __shfl_down(s, o, 64);
    __shared__ float red[TPB / 64];
    if ((threadIdx.x & 63) == 0) red[threadIdx.x >> 6] = s;
    __syncthreads();
    if (threadIdx.x == 0)
        atomicAdd(sqsum, red[0] + red[1] + red[2] + red[3]);
}

// ---- path A (big ws): fused combine+gather, res in ws (no alias race) ----
__global__ void gatherF_kernel(const float* __restrict__ z, const int* __restrict__ zc,
        const float* __restrict__ cb, const float4* __restrict__ res,
        float* __restrict__ out, unsigned* __restrict__ counts,
        float* __restrict__ sqsum, unsigned* __restrict__ list,
        unsigned* __restrict__ lcount) {
    int vox = blockIdx.x * blockDim.x + threadIdx.x;
    float v1 = -INFINITY, v2 = -INFINITY; int idx = 0;
#pragma unroll
    for (int h = 0; h < NSPLIT; ++h) {
        float4 t4 = res[(size_t)h * NVOX + vox];
        float a1 = t4.x, a2 = t4.y; int ai = __float_as_int(t4.z);
        float mn = fminf(v1, a1);
        v2 = fmaxf(fmaxf(v2, a2), mn);
        if (a1 > v1) { v1 = a1; idx = ai; }
    }
    float s = 0.f;
    if (v1 - v2 < CERT_EPS) {
        unsigned pos = atomicAdd(lcount, 1u);
        list[pos] = vox;
    } else {
        const float4* crow = (const float4*)(cb + (size_t)idx * DIM);
        const float4* zrow = (const float4*)(z + (size_t)vox * DIM);
        float4* qrow = (float4*)(out + OFF_Q + (size_t)vox * DIM);
#pragma unroll
        for (int i = 0; i < DIM / 4; ++i) {
            float4 c4 = crow[i];
            float4 z4 = zrow[i];
            float dx = z4.x - c4.x, dy = z4.y - c4.y;
            float dz = z4.z - c4.z, dw = z4.w - c4.w;
            s += dx * dx + dy * dy + dz * dz + dw * dw;
            qrow[i] = c4;
        }
        out[OFF_IDX + vox] = (float)idx;
        atomicAdd(&counts[zc[vox * 4] * NUM_EMB + idx], 1u);
    }
#pragma unroll
    for (int o = 32; o > 0; o >>= 1) s += __shfl_down(s, o, 64);
    __shared__ float red[TPB / 64];
    if ((threadIdx.x & 63) == 0) red[threadIdx.x >> 6] = s;
    __syncthreads();
    if (threadIdx.x == 0)
        atomicAdd(sqsum, red[0] + red[1] + red[2] + red[3]);
}

// Repair scan: (flagged row, 512-entry chunk) items over 2048 waves;
// coalesced 4-entry groups, x4 interleaved reduce chains; exact f32 dists
// merged via packed (sortable<<32)|idx u64 atomicMin (lowest-idx ties).
__global__ void repair_scan_kernel(const float* __restrict__ z,
        const float* __restrict__ cb, const unsigned* __restrict__ list,
        const unsigned* __restrict__ lcount,
        unsigned long long* __restrict__ merge) {
    int wid = (blockIdx.x * blockDim.x + threadIdx.x) >> 6;
    int l   = threadIdx.x & 63;
    int nw  = (gridDim.x * blockDim.x) >> 6;
    int nitems = (int)*lcount * (NUM_EMB / RCH);
    int sub = l & 15, ent = l >> 4;

    for (int it = wid; it < nitems; it += nw) {
        int k    = it / (NUM_EMB / RCH);
        int base = (it % (NUM_EMB / RCH)) * RCH;
        int vox  = list[k];
        float4 z4 = ((const float4*)(z + (size_t)vox * DIM))[sub];
        float m = INFINITY; int mi = 0;

        for (int g0 = 0; g0 < RCH / 4; g0 += 4) {
            float d[4];
#pragma unroll
            for (int u = 0; u < 4; ++u) {
                int e = base + (g0 + u) * 4 + ent;
                float4 c4 = ((const float4*)(cb + (size_t)e * DIM))[sub];
                float dx = z4.x - c4.x, dy = z4.y - c4.y;
                float dz = z4.z - c4.z, dw = z4.w - c4.w;
                d[u] = fmaf(dx, dx, fmaf(dy, dy, fmaf(dz, dz, dw * dw)));
            }
#pragma unroll
            for (int st = 1; st < 16; st <<= 1)
#pragma unroll
                for (int u = 0; u < 4; ++u) d[u] += __shfl_xor(d[u], st, 16);
#pragma unroll
            for (int u = 0; u < 4; ++u) {
                int e = base + (g0 + u) * 4 + ent;
                if (d[u] < m) { m = d[u]; mi = e; }
            }
        }
#pragma unroll
        for (int st = 32; st > 0; st >>= 1) {
            float om = __shfl_xor(m, st, 64);
            int   oi = __shfl_xor(mi, st, 64);
            if (om < m || (om == m && oi < mi)) { m = om; mi = oi; }
        }
        if (l == 0) {
            unsigned long long key =
                ((unsigned long long)fmap(m) << 32) | (unsigned)mi;
            atomicMin(&merge[vox], key);
        }
    }
}

__global__ void repair_apply_kernel(const float* __restrict__ z,
        const int* __restrict__ zc, const float* __restrict__ cb,
        const unsigned* __restrict__ list, const unsigned* __restrict__ lcount,
        const unsigned long long* __restrict__ merge, float* __restrict__ out,
        unsigned* __restrict__ counts, float* __restrict__ sqsum) {
    int wid = (blockIdx.x * blockDim.x + threadIdx.x) >> 6;
    int l   = threadIdx.x & 63;
    int n   = (int)*lcount;
    int nw  = (gridDim.x * blockDim.x) >> 6;
    for (int k = wid; k < n; k += nw) {
        int vox = list[k];
        int mi  = (int)(merge[vox] & 0xFFFFFFFFull);
        float cv = cb[(size_t)mi * DIM + l];
        float zv = z[(size_t)vox * DIM + l];
        out[OFF_Q + (size_t)vox * DIM + l] = cv;
        float df = zv - cv;
        float s = df * df;
#pragma unroll
        for (int st = 32; st > 0; st >>= 1) s += __shfl_xor(s, st, 64);
        if (l == 0) {
            out[OFF_IDX + vox] = (float)mi;
            atomicAdd(&counts[zc[vox * 4] * NUM_EMB + mi], 1u);
            atomicAdd(sqsum, s);
        }
    }
}

// per-batch entropy/unique + fused finalize via atomicAdd on zeroed scalars
__global__ void stats_final_kernel(const unsigned* __restrict__ counts,
                                   const float* __restrict__ sqsum,
                                   float* __restrict__ out) {
    int b = blockIdx.x;
    const unsigned* c = counts + b * NUM_EMB;

    __shared__ float sred[TPB / 64];
    float nf = 0.f;
    for (int i = threadIdx.x; i < NUM_EMB; i += TPB) nf += (float)c[i];
#pragma unroll
    for (int o = 32; o > 0; o >>= 1) nf += __shfl_down(nf, o, 64);
    if ((threadIdx.x & 63) == 0) sred[threadIdx.x >> 6] = nf;
    __syncthreads();
    float n = sred[0] + sred[1] + sred[2] + sred[3];
    __syncthreads();

    float ent = 0.f, uniq = 0.f;
    for (int i = threadIdx.x; i < NUM_EMB; i += TPB) {
        unsigned ci = c[i];
        if (ci) {
            float p = (float)ci / n;
            ent -= p * logf(p + 1e-10f);
            uniq += 1.f;
        }
    }
#pragma unroll
    for (int o = 32; o > 0; o >>= 1) {
        ent  += __shfl_down(ent, o, 64);
        uniq += __shfl_down(uniq, o, 64);
    }
    __shared__ float e4[TPB / 64], u4[TPB / 64];
    if ((threadIdx.x & 63) == 0) { e4[threadIdx.x >> 6] = ent; u4[threadIdx.x >> 6] = uniq; }
    __syncthreads();
    if (threadIdx.x == 0) {
        float eb = e4[0] + e4[1] + e4[2] + e4[3];
        float ub = u4[0] + u4[1] + u4[2] + u4[3];
        atomicAdd(&out[OFF_ENT],  eb * 0.25f);
        atomicAdd(&out[OFF_PERP], expf(eb) * 0.25f);
        atomicAdd(&out[OFF_UNIQ], ub * 0.25f);
        atomicAdd(&out[OFF_UTIL], ub * (100.f / (4.f * NUM_EMB)));
        if (b == 0) {
            float loss = *sqsum / (float)((size_t)NVOX * DIM);
            out[OFF_VQ]   = loss;
            out[OFF_COMM] = loss;
        }
    }
}

extern "C" void kernel_launch(void* const* d_in, const int* in_sizes, int n_in,
                              void* d_out, int out_size, void* d_ws, size_t ws_size,
                              hipStream_t stream) {
    const float* z  = (const float*)d_in[0];
    const int*   zc = (const int*)d_in[1];
    const float* cb = (const float*)d_in[2];
    float* out = (float*)d_out;
    char* ws = (char*)d_ws;

    // d_out scratch: cbh 1MB | cbm 1MB at Q rows 0..16383 (overwritten later).
    unsigned short* cbh = (unsigned short*)out;
    unsigned short* cbm = cbh + NUM_EMB * DIM;

    unsigned* counts = (unsigned*)ws;                       // 131072 B
    unsigned* list   = (unsigned*)(ws + 131072);            // 131072 B
    unsigned* misc   = (unsigned*)(ws + 262144);            // 64 B
    unsigned* lcount = misc;
    float*    sqsum  = (float*)(ws + 262148);
    float*    cnn    = (float*)(ws + 262208);               // 32768 B
    unsigned long long* merge = (unsigned long long*)(ws + 294976); // 262144 B
    // path A: res in ws (2MB) -> fused combine+gather (no alias race)
    size_t res_ws_off = 557120;
    bool bigws = ws_size >= res_ws_off + (size_t)NSPLIT * NVOX * 16;
    float4* res = bigws ? (float4*)(ws + res_ws_off)
                        : (float4*)(out + 524288);          // path B: in d_out

    prep_kernel<<<NUM_EMB / 4, TPB, 0, stream>>>(cb, cbh, cbm, cnn,
                                                 counts, misc, merge, out);
    argmin_kernel<<<(NVOX / 128) * NSPLIT, TPB, 0, stream>>>(z, cbh, cbm, cnn, res);
    if (bigws) {
        gatherF_kernel<<<NVOX / TPB, TPB, 0, stream>>>(z, zc, cb, res, out,
                                                       counts, sqsum, list, lcount);
    } else {
        combine_kernel<<<NVOX / TPB, TPB, 0, stream>>>(res, out);
        gather_kernel<<<NVOX / TPB, TPB, 0, stream>>>(z, zc, cb, out, counts,
                                                      sqsum, list, lcount);
    }
    repair_scan_kernel<<<512, TPB, 0, stream>>>(z, cb, list, lcount, merge);
    repair_apply_kernel<<<64, TPB, 0, stream>>>(z, zc, cb, list, lcount, merge,
                                                out, counts, sqsum);
    stats_final_kernel<<<NBATCH, TPB, 0, stream>>>(counts, sqsum, out);
}

// Round 11
// 203.998 us; speedup vs baseline: 1.0668x; 1.0668x over previous
//
#include <hip/hip_runtime.h>
#include <math.h>

#define NUM_EMB 8192
#define DIM     64
#define NBATCH  4
#define NVOX    32768
#define TPB     256               // block size for the small kernels
#define TPBA    512               // argmin: 8 waves/block
#define NSPLIT  8                 // codebook splits
#define EPB     (NUM_EMB / NSPLIT)
#define CHUNK   64                // entries staged per iteration
#define NCH     (EPB / CHUNK)     // 16 chunks
#define BUFSZ   (CHUNK * 128 * 2 + CHUNK * 4)   // lbh 8K | lbm 8K | cn 256B
#define CERT_EPS 0.015f           // v-space gap threshold (err bound ~3.2e-3)
#define RCH     512               // repair: entries per (row,chunk) work item

// output layout (f32, concatenated in return order)
#define OFF_Q     0            // 32768*64
#define OFF_VQ    2097152
#define OFF_COMM  2097153
#define OFF_IDX   2097154      // 32768
#define OFF_PERP  2129922
#define OFF_ENT   2129923
#define OFF_UNIQ  2129924
#define OFF_UTIL  2129925

typedef __bf16 bf16x8 __attribute__((ext_vector_type(8)));
typedef float  f32x4  __attribute__((ext_vector_type(4)));

__device__ __forceinline__ unsigned short f2bf(float f) {   // RNE f32->bf16
    unsigned u = __float_as_uint(f);
    unsigned r = u + 0x7FFFu + ((u >> 16) & 1u);
    return (unsigned short)(r >> 16);
}
__device__ __forceinline__ float bf2f(unsigned short h) {
    return __uint_as_float(((unsigned)h) << 16);
}
// monotone float -> sortable uint (non-NaN)
__device__ __forceinline__ unsigned fmap(float f) {
    unsigned u = __float_as_uint(f);
    return (u & 0x80000000u) ? ~u : (u | 0x80000000u);
}

// prep: bf16 2-split of codebook, scalar -||c||^2/2, all scratch init,
// and zeroing of the 6 scalar outputs (poisoned 0xAA; stats atomicAdds).
__global__ void prep_kernel(const float* __restrict__ cb,
                            unsigned short* __restrict__ cbh,
                            unsigned short* __restrict__ cbm,
                            float* __restrict__ cnn,
                            unsigned* __restrict__ counts,
                            unsigned* __restrict__ misc,
                            unsigned long long* __restrict__ merge,
                            float* __restrict__ out) {
    int row = blockIdx.x * 4 + (threadIdx.x >> 6);
    int l   = threadIdx.x & 63;
    float f = cb[row * DIM + l];
    unsigned short hh = f2bf(f); float r1 = f - bf2f(hh);
    cbh[row * DIM + l] = hh;
    cbm[row * DIM + l] = f2bf(r1);
    float s = f * f;
#pragma unroll
    for (int o = 32; o > 0; o >>= 1) s += __shfl_xor(s, o, 64);
    if (l == 0) cnn[row] = -0.5f * s;

    int gid = blockIdx.x * TPB + threadIdx.x;       // 0..524287
    if (gid < NBATCH * NUM_EMB) counts[gid] = 0;
    if (gid >= 32768 && gid < 65536) merge[gid - 32768] = ~0ull;
    if (gid < 16) misc[gid] = 0;                    // lcount, sqsum, pad
    if (blockIdx.x == 0) {
        if (threadIdx.x < 2) out[OFF_VQ + threadIdx.x] = 0.f;
        if (threadIdx.x < 4) out[OFF_PERP + threadIdx.x] = 0.f;
    }
}

// Single-pass 3-product (hh,hm,mh) MFMA scan.
// r11: 8 waves/block (256 vox), dbuf with ONE barrier per chunk.
// Rationale (r10 PM): VALUBusy includes MFMA issue -> pure VALU ~10%, the
// limiter is barrier serialization + staging redundancy, so amortize each
// barrier over 2x MFMA and halve per-voxel staging. Inner loop unchanged.
__global__ __launch_bounds__(TPBA) void argmin_kernel(
        const float* __restrict__ z,
        const unsigned short* __restrict__ cbh,
        const unsigned short* __restrict__ cbm,
        const float* __restrict__ cnn,
        float4* __restrict__ res) {
    __shared__ __align__(16) char lds[2 * BUFSZ];

    const int t  = threadIdx.x;
    const int l  = t & 63, w = t >> 6;               // 8 waves
    const int lc = l & 15, lg = l >> 4;
    const int vb = blockIdx.x >> 3, qh = blockIdx.x & 7;
    const int ebase = qh * EPB;

    union U { bf16x8 v; unsigned short s[8]; };
    U Ah[2][2], Am[2][2];                // on-the-fly 2-split of 32 z rows
#pragma unroll
    for (int set = 0; set < 2; ++set) {
        const float* zp = z + (size_t)(vb * 256 + w * 32 + set * 16 + lc) * DIM + lg * 8;
#pragma unroll
        for (int ks = 0; ks < 2; ++ks)
#pragma unroll
            for (int j = 0; j < 8; ++j) {
                float f = zp[ks * 32 + j];
                unsigned short hh = f2bf(f);
                Ah[set][ks].s[j] = hh;
                Am[set][ks].s[j] = f2bf(f - bf2f(hh));
            }
    }

    float m1[2][4], m2[2][4]; int ix[2][4];
#pragma unroll
    for (int set = 0; set < 2; ++set)
#pragma unroll
        for (int r = 0; r < 4; ++r) {
            m1[set][r] = -INFINITY; m2[set][r] = -INFINITY; ix[set][r] = 0;
        }

    // per-lane LDS read bases: XOR-swizzle folded once; k-step1 = base ^ 64
    const int b0 = (lc * 128 + lg * 16) ^ ((lc & 7) << 4);
    const int b1 = b0 ^ 64;

    // staging: 512 threads x one uint4 per array per chunk (16KB total)
    uint4 rh0, rm0; float rc;
#define STAGE_LOAD(CH) {                                                      \
        const uint4* sh = (const uint4*)(cbh + (size_t)(ebase + (CH) * CHUNK) * DIM); \
        const uint4* sm = (const uint4*)(cbm + (size_t)(ebase + (CH) * CHUNK) * DIM); \
        rh0 = sh[t]; rm0 = sm[t];                                             \
        if (t < CHUNK) rc = cnn[ebase + (CH) * CHUNK + t];                    \
    }
#define STAGE_WRITE(BUF) {                                                    \
        int o0 = t * 16;                                                      \
        int s0 = o0 ^ (((o0 >> 7) & 7) << 4);                                 \
        *(uint4*)((BUF) + s0) = rh0;                                          \
        *(uint4*)((BUF) + 8192 + s0) = rm0;                                   \
        if (t < CHUNK) ((float*)((BUF) + 16384))[t] = rc;                     \
    }

    STAGE_LOAD(0);
    STAGE_WRITE(lds);
    __syncthreads();

    for (int ch = 0; ch < NCH; ++ch) {
        char* cur = lds + (ch & 1) * BUFSZ;
        if (ch + 1 < NCH) STAGE_LOAD(ch + 1);      // issue early; hides under MFMA

        int e0 = ebase + ch * CHUNK + lc;
#pragma unroll
        for (int tile = 0; tile < CHUNK / 16; ++tile) {
            bf16x8 bh0 = *(const bf16x8*)(cur + b0 + tile * 2048);
            bf16x8 bh1 = *(const bf16x8*)(cur + b1 + tile * 2048);
            bf16x8 bm0 = *(const bf16x8*)(cur + 8192 + b0 + tile * 2048);
            bf16x8 bm1 = *(const bf16x8*)(cur + 8192 + b1 + tile * 2048);
            float  cnv = *(const float*)(cur + 16384 + (tile * 16 + lc) * 4);
            f32x4 c0 = {cnv, cnv, cnv, cnv};
            int eidx = e0 + tile * 16;
#pragma unroll
            for (int set = 0; set < 2; ++set) {
                f32x4 a = c0;                     // C-init = -||c||^2/2
                a = __builtin_amdgcn_mfma_f32_16x16x32_bf16(Ah[set][0].v, bh0, a, 0, 0, 0);
                a = __builtin_amdgcn_mfma_f32_16x16x32_bf16(Am[set][0].v, bh0, a, 0, 0, 0);
                a = __builtin_amdgcn_mfma_f32_16x16x32_bf16(Ah[set][0].v, bm0, a, 0, 0, 0);
                a = __builtin_amdgcn_mfma_f32_16x16x32_bf16(Ah[set][1].v, bh1, a, 0, 0, 0);
                a = __builtin_amdgcn_mfma_f32_16x16x32_bf16(Am[set][1].v, bh1, a, 0, 0, 0);
                a = __builtin_amdgcn_mfma_f32_16x16x32_bf16(Ah[set][1].v, bm1, a, 0, 0, 0);
#pragma unroll
                for (int r = 0; r < 4; ++r) {     // D: col=lc, row=lg*4+r (m89)
                    float v = a[r];               // = z.c - ||c||^2/2 exactly
                    m2[set][r] = __builtin_amdgcn_fmed3f(v, m1[set][r], m2[set][r]);
                    if (v > m1[set][r]) { m1[set][r] = v; ix[set][r] = eidx; }
                }
            }
        }
        if (ch + 1 < NCH) STAGE_WRITE(lds + ((ch + 1) & 1) * BUFSZ);
        __syncthreads();   // single barrier/chunk: prev-iter barrier protects
    }                      // the buffer being overwritten (write-before-bar)

    // reduce (max1,idx,max2) across the 16 column-lanes, lowest-idx tiebreak
#pragma unroll
    for (int set = 0; set < 2; ++set)
#pragma unroll
        for (int r = 0; r < 4; ++r) {
            float v1 = m1[set][r], v2 = m2[set][r]; int i1 = ix[set][r];
#pragma unroll
            for (int st = 1; st < 16; st <<= 1) {
                float o1 = __shfl_xor(v1, st, 16);
                float o2 = __shfl_xor(v2, st, 16);
                int   oi = __shfl_xor(i1, st, 16);
                float mn = fminf(v1, o1);
                v2 = fmaxf(fmaxf(v2, o2), mn);
                if (o1 > v1 || (o1 == v1 && oi < i1)) { v1 = o1; i1 = oi; }
            }
            if (lc == 0) {
                int vox = vb * 256 + w * 32 + set * 16 + lg * 4 + r;
                res[(size_t)qh * NVOX + vox] =
                    make_float4(v1, v2, __int_as_float(i1), 0.f);
            }
        }
}

// ---- path B (small ws): combine then gather, res in d_out ----
__global__ void combine_kernel(const float4* __restrict__ res, float* __restrict__ out) {
    int vox = blockIdx.x * blockDim.x + threadIdx.x;
    float v1 = -INFINITY, v2 = -INFINITY; int idx = 0;
#pragma unroll
    for (int h = 0; h < NSPLIT; ++h) {
        float4 t4 = res[(size_t)h * NVOX + vox];
        float a1 = t4.x, a2 = t4.y; int ai = __float_as_int(t4.z);
        float mn = fminf(v1, a1);
        v2 = fmaxf(fmaxf(v2, a2), mn);
        if (a1 > v1) { v1 = a1; idx = ai; }   // strict >: earlier split wins ties
    }
    unsigned flag = (v1 - v2 < CERT_EPS) ? 0x80000000u : 0u;
    ((unsigned*)out)[OFF_IDX + vox] = (unsigned)idx | flag;
}

__global__ void gather_kernel(const float* __restrict__ z, const int* __restrict__ zc,
        const float* __restrict__ cb, float* __restrict__ out,
        unsigned* __restrict__ counts, float* __restrict__ sqsum,
        unsigned* __restrict__ list, unsigned* __restrict__ lcount) {
    int vox = blockIdx.x * blockDim.x + threadIdx.x;
    unsigned pk = ((unsigned*)out)[OFF_IDX + vox];
    float s = 0.f;
    if (pk & 0x80000000u) {
        unsigned pos = atomicAdd(lcount, 1u);
        list[pos] = vox;
    } else {
        unsigned idx = pk;
        const float4* crow = (const float4*)(cb + (size_t)idx * DIM);
        const float4* zrow = (const float4*)(z + (size_t)vox * DIM);
        float4* qrow = (float4*)(out + OFF_Q + (size_t)vox * DIM);
#pragma unroll
        for (int i = 0; i < DIM / 4; ++i) {
            float4 c4 = crow[i];
            float4 z4 = zrow[i];
            float dx = z4.x - c4.x, dy = z4.y - c4.y;
            float dz = z4.z - c4.z, dw = z4.w - c4.w;
            s += dx * dx + dy * dy + dz * dz + dw * dw;
            qrow[i] = c4;
        }
        out[OFF_IDX + vox] = (float)idx;
        atomicAdd(&counts[zc[vox * 4] * NUM_EMB + idx], 1u);
    }
#pragma unroll
    for (int o = 32; o > 0; o >>= 1) s += __shfl_down(s, o, 64);
    __shared__ float red[TPB / 64];
    if ((threadIdx.x & 63) == 0) red[threadIdx.x >> 6] = s;
    __syncthreads();
    if (threadIdx.x == 0)
        atomicAdd(sqsum, red[0] + red[1] + red[2] + red[3]);
}

// ---- path A (big ws): fused combine+gather, res in ws (no alias race) ----
__global__ void gatherF_kernel(const float* __restrict__ z, const int* __restrict__ zc,
        const float* __restrict__ cb, const float4* __restrict__ res,
        float* __restrict__ out, unsigned* __restrict__ counts,
        float* __restrict__ sqsum, unsigned* __restrict__ list,
        unsigned* __restrict__ lcount) {
    int vox = blockIdx.x * blockDim.x + threadIdx.x;
    float v1 = -INFINITY, v2 = -INFINITY; int idx = 0;
#pragma unroll
    for (int h = 0; h < NSPLIT; ++h) {
        float4 t4 = res[(size_t)h * NVOX + vox];
        float a1 = t4.x, a2 = t4.y; int ai = __float_as_int(t4.z);
        float mn = fminf(v1, a1);
        v2 = fmaxf(fmaxf(v2, a2), mn);
        if (a1 > v1) { v1 = a1; idx = ai; }
    }
    float s = 0.f;
    if (v1 - v2 < CERT_EPS) {
        unsigned pos = atomicAdd(lcount, 1u);
        list[pos] = vox;
    } else {
        const float4* crow = (const float4*)(cb + (size_t)idx * DIM);
        const float4* zrow = (const float4*)(z + (size_t)vox * DIM);
        float4* qrow = (float4*)(out + OFF_Q + (size_t)vox * DIM);
#pragma unroll
        for (int i = 0; i < DIM / 4; ++i) {
            float4 c4 = crow[i];
            float4 z4 = zrow[i];
            float dx = z4.x - c4.x, dy = z4.y - c4.y;
            float dz = z4.z - c4.z, dw = z4.w - c4.w;
            s += dx * dx + dy * dy + dz * dz + dw * dw;
            qrow[i] = c4;
        }
        out[OFF_IDX + vox] = (float)idx;
        atomicAdd(&counts[zc[vox * 4] * NUM_EMB + idx], 1u);
    }
#pragma unroll
    for (int o = 32; o > 0; o >>= 1) s += __shfl_down(s, o, 64);
    __shared__ float red[TPB / 64];
    if ((threadIdx.x & 63) == 0) red[threadIdx.x >> 6] = s;
    __syncthreads();
    if (threadIdx.x == 0)
        atomicAdd(sqsum, red[0] + red[1] + red[2] + red[3]);
}

// Repair scan: (flagged row, 512-entry chunk) items over 2048 waves;
// coalesced 4-entry groups, x4 interleaved reduce chains; exact f32 dists
// merged via packed (sortable<<32)|idx u64 atomicMin (lowest-idx ties).
__global__ void repair_scan_kernel(const float* __restrict__ z,
        const float* __restrict__ cb, const unsigned* __restrict__ list,
        const unsigned* __restrict__ lcount,
        unsigned long long* __restrict__ merge) {
    int wid = (blockIdx.x * blockDim.x + threadIdx.x) >> 6;
    int l   = threadIdx.x & 63;
    int nw  = (gridDim.x * blockDim.x) >> 6;
    int nitems = (int)*lcount * (NUM_EMB / RCH);
    int sub = l & 15, ent = l >> 4;

    for (int it = wid; it < nitems; it += nw) {
        int k    = it / (NUM_EMB / RCH);
        int base = (it % (NUM_EMB / RCH)) * RCH;
        int vox  = list[k];
        float4 z4 = ((const float4*)(z + (size_t)vox * DIM))[sub];
        float m = INFINITY; int mi = 0;

        for (int g0 = 0; g0 < RCH / 4; g0 += 4) {
            float d[4];
#pragma unroll
            for (int u = 0; u < 4; ++u) {
                int e = base + (g0 + u) * 4 + ent;
                float4 c4 = ((const float4*)(cb + (size_t)e * DIM))[sub];
                float dx = z4.x - c4.x, dy = z4.y - c4.y;
                float dz = z4.z - c4.z, dw = z4.w - c4.w;
                d[u] = fmaf(dx, dx, fmaf(dy, dy, fmaf(dz, dz, dw * dw)));
            }
#pragma unroll
            for (int st = 1; st < 16; st <<= 1)
#pragma unroll
                for (int u = 0; u < 4; ++u) d[u] += __shfl_xor(d[u], st, 16);
#pragma unroll
            for (int u = 0; u < 4; ++u) {
                int e = base + (g0 + u) * 4 + ent;
                if (d[u] < m) { m = d[u]; mi = e; }
            }
        }
#pragma unroll
        for (int st = 32; st > 0; st >>= 1) {
            float om = __shfl_xor(m, st, 64);
            int   oi = __shfl_xor(mi, st, 64);
            if (om < m || (om == m && oi < mi)) { m = om; mi = oi; }
        }
        if (l == 0) {
            unsigned long long key =
                ((unsigned long long)fmap(m) << 32) | (unsigned)mi;
            atomicMin(&merge[vox], key);
        }
    }
}

__global__ void repair_apply_kernel(const float* __restrict__ z,
        const int* __restrict__ zc, const float* __restrict__ cb,
        const unsigned* __restrict__ list, const unsigned* __restrict__ lcount,
        const unsigned long long* __restrict__ merge, float* __restrict__ out,
        unsigned* __restrict__ counts, float* __restrict__ sqsum) {
    int wid = (blockIdx.x * blockDim.x + threadIdx.x) >> 6;
    int l   = threadIdx.x & 63;
    int n   = (int)*lcount;
    int nw  = (gridDim.x * blockDim.x) >> 6;
    for (int k = wid; k < n; k += nw) {
        int vox = list[k];
        int mi  = (int)(merge[vox] & 0xFFFFFFFFull);
        float cv = cb[(size_t)mi * DIM + l];
        float zv = z[(size_t)vox * DIM + l];
        out[OFF_Q + (size_t)vox * DIM + l] = cv;
        float df = zv - cv;
        float s = df * df;
#pragma unroll
        for (int st = 32; st > 0; st >>= 1) s += __shfl_xor(s, st, 64);
        if (l == 0) {
            out[OFF_IDX + vox] = (float)mi;
            atomicAdd(&counts[zc[vox * 4] * NUM_EMB + mi], 1u);
            atomicAdd(sqsum, s);
        }
    }
}

// per-batch entropy/unique + fused finalize via atomicAdd on zeroed scalars
__global__ void stats_final_kernel(const unsigned* __restrict__ counts,
                                   const float* __restrict__ sqsum,
                                   float* __restrict__ out) {
    int b = blockIdx.x;
    const unsigned* c = counts + b * NUM_EMB;

    __shared__ float sred[TPB / 64];
    float nf = 0.f;
    for (int i = threadIdx.x; i < NUM_EMB; i += TPB) nf += (float)c[i];
#pragma unroll
    for (int o = 32; o > 0; o >>= 1) nf += __shfl_down(nf, o, 64);
    if ((threadIdx.x & 63) == 0) sred[threadIdx.x >> 6] = nf;
    __syncthreads();
    float n = sred[0] + sred[1] + sred[2] + sred[3];
    __syncthreads();

    float ent = 0.f, uniq = 0.f;
    for (int i = threadIdx.x; i < NUM_EMB; i += TPB) {
        unsigned ci = c[i];
        if (ci) {
            float p = (float)ci / n;
            ent -= p * logf(p + 1e-10f);
            uniq += 1.f;
        }
    }
#pragma unroll
    for (int o = 32; o > 0; o >>= 1) {
        ent  += __shfl_down(ent, o, 64);
        uniq += __shfl_down(uniq, o, 64);
    }
    __shared__ float e4[TPB / 64], u4[TPB / 64];
    if ((threadIdx.x & 63) == 0) { e4[threadIdx.x >> 6] = ent; u4[threadIdx.x >> 6] = uniq; }
    __syncthreads();
    if (threadIdx.x == 0) {
        float eb = e4[0] + e4[1] + e4[2] + e4[3];
        float ub = u4[0] + u4[1] + u4[2] + u4[3];
        atomicAdd(&out[OFF_ENT],  eb * 0.25f);
        atomicAdd(&out[OFF_PERP], expf(eb) * 0.25f);
        atomicAdd(&out[OFF_UNIQ], ub * 0.25f);
        atomicAdd(&out[OFF_UTIL], ub * (100.f / (4.f * NUM_EMB)));
        if (b == 0) {
            float loss = *sqsum / (float)((size_t)NVOX * DIM);
            out[OFF_VQ]   = loss;
            out[OFF_COMM] = loss;
        }
    }
}

extern "C" void kernel_launch(void* const* d_in, const int* in_sizes, int n_in,
                              void* d_out, int out_size, void* d_ws, size_t ws_size,
                              hipStream_t stream) {
    const float* z  = (const float*)d_in[0];
    const int*   zc = (const int*)d_in[1];
    const float* cb = (const float*)d_in[2];
    float* out = (float*)d_out;
    char* ws = (char*)d_ws;

    // d_out scratch: cbh 1MB | cbm 1MB at Q floats [0, 524288).
    unsigned short* cbh = (unsigned short*)out;
    unsigned short* cbm = cbh + NUM_EMB * DIM;

    unsigned* counts = (unsigned*)ws;                       // 131072 B
    unsigned* list   = (unsigned*)(ws + 131072);            // 131072 B
    unsigned* misc   = (unsigned*)(ws + 262144);            // 64 B
    unsigned* lcount = misc;
    float*    sqsum  = (float*)(ws + 262148);
    float*    cnn    = (float*)(ws + 262208);               // 32768 B
    unsigned long long* merge = (unsigned long long*)(ws + 294976); // 262144 B
    // path A: res in ws (4MB) -> fused combine+gather (no alias race)
    size_t res_ws_off = 557120;
    bool bigws = ws_size >= res_ws_off + (size_t)NSPLIT * NVOX * 16;
    float4* res = bigws ? (float4*)(ws + res_ws_off)
                        : (float4*)(out + 524288);  // path B: floats [524288, 1572864) < OFF_VQ

    prep_kernel<<<NUM_EMB / 4, TPB, 0, stream>>>(cb, cbh, cbm, cnn,
                                                 counts, misc, merge, out);
    argmin_kernel<<<(NVOX / 256) * NSPLIT, TPBA, 0, stream>>>(z, cbh, cbm, cnn, res);
    if (bigws) {
        gatherF_kernel<<<NVOX / TPB, TPB, 0, stream>>>(z, zc, cb, res, out,
                                                       counts, sqsum, list, lcount);
    } else {
        combine_kernel<<<NVOX / TPB, TPB, 0, stream>>>(res, out);
        gather_kernel<<<NVOX / TPB, TPB, 0, stream>>>(z, zc, cb, out, counts,
                                                      sqsum, list, lcount);
    }
    repair_scan_kernel<<<512, TPB, 0, stream>>>(z, cb, list, lcount, merge);
    repair_apply_kernel<<<64, TPB, 0, stream>>>(z, zc, cb, list, lcount, merge,
                                                out, counts, sqsum);
    stats_final_kernel<<<NBATCH, TPB, 0, stream>>>(counts, sqsum, out);
}